// Round 4
// baseline (534.559 us; speedup 1.0000x reference)
//
#include <hip/hip_runtime.h>

// CRAFT OHEM loss, round 8.
// R7 -> R8: R7 proved the conflict fix (SQ_LDS_BANK_CONFLICT 2.74M -> 0) but
// LOST occupancy (32 KB LDS -> 4 blocks/CU, 66% -> 36%) and got slower
// (115 -> 146 us). All pipes idle (VALU 12%, HBM 14%) => concurrency-starved.
// R8 keeps the private conflict-free histogram but shares a column per thread
// PAIR (hist[2][16][128], col=tid>>1): 16 KB/block -> 8 blocks/CU at
// launch_bounds(256,8), VGPR<=64 tier. Lanes l,l^1 share a bank (2/bank
// uniform = free). EPB 8192 -> 4096 (finer tail, byte counters max 32).
// k_refine: skip round-A histogram when T1>0 (top bits degenerate).

constexpr int   BATCH   = 32;
constexpr int   NPS     = 768 * 768;            // 589824
constexpr int   CH2     = BATCH * 2;            // 64
constexpr int   EPB     = 4096;                 // pixels per block
constexpr int   BX      = NPS / EPB;            // 144
constexpr float POS_THR_F = 0.1f;
constexpr unsigned TOPK_NO_POS = 500u;
constexpr int   NB1     = 64;                   // stage-1 bins (quarter-octave)
constexpr int   RAW_OFF = 448;                  // exp 112 << 2
constexpr int   CAP     = 131072;               // global compact buffer per channel
constexpr int   CAPB    = 1024;                 // LDS staging per channel per block

__device__ __forceinline__ unsigned bin_of(float v) {
    int b = (int)(__float_as_uint(v) >> 21) - RAW_OFF;   // v in [0,1): raw <= 507
    return b < 0 ? 0u : (unsigned)b;                      // 0..59
}

// ---------------------------------------------------------------------------
// Pass 1: pair-private u8-packed 64-bin histogram per channel
// (2 lanes/bank uniform -> conflict-free) + positive stats.
// ---------------------------------------------------------------------------
__global__ __launch_bounds__(256, 8) void k_hist(
    const float4* __restrict__ pred4,
    const float4* __restrict__ reg4,
    const float4* __restrict__ aff4,
    unsigned* __restrict__ h1c,
    unsigned* __restrict__ pcnt, float* __restrict__ psum)
{
    __shared__ unsigned hist[2][16][128];   // [ch][word=bin>>2][col=tid>>1], u8x4
    __shared__ unsigned wpc[8];
    __shared__ float    wps[8];
    for (int j = threadIdx.x; j < 2*16*128; j += 256) ((unsigned*)hist)[j] = 0u;
    __syncthreads();

    const int  b   = blockIdx.y;
    const int  tid = threadIdx.x;
    const int  col = tid >> 1;
    constexpr int ITERS = EPB / 1024;            // 4
    long idx4 = (((long)b * NPS + (long)blockIdx.x * EPB) >> 2) + tid;

    unsigned pc0 = 0, pc1 = 0;
    float    ps0 = 0.f, ps1 = 0.f;

    for (int i = 0; i < ITERS; ++i) {
        const float4 r  = reg4[idx4];
        const float4 a  = aff4[idx4];
        const float4 pA = pred4[idx4 * 2];
        const float4 pB = pred4[idx4 * 2 + 1];
#define DO_PIX(RR, AA, PG, PA) do {                                           \
        float d0 = (PG) - (RR); float v0 = d0 * d0;                           \
        if ((RR) >= POS_THR_F) { pc0++; ps0 += v0; }                          \
        else { unsigned bn = bin_of(v0);                                      \
               atomicAdd(&hist[0][bn>>2][col], 1u << ((bn&3)*8)); }           \
        float d1 = (PA) - (AA); float v1 = d1 * d1;                           \
        if ((AA) >= POS_THR_F) { pc1++; ps1 += v1; }                          \
        else { unsigned bn = bin_of(v1);                                      \
               atomicAdd(&hist[1][bn>>2][col], 1u << ((bn&3)*8)); }           \
    } while (0)
        DO_PIX(r.x, a.x, pA.x, pA.y);
        DO_PIX(r.y, a.y, pA.z, pA.w);
        DO_PIX(r.z, a.z, pB.x, pB.y);
        DO_PIX(r.w, a.w, pB.z, pB.w);
#undef DO_PIX
        idx4 += 256;
    }
    __syncthreads();

    // Merge: wave wid owns 8 (ch,word) pairs; lane sums 2 columns (u8x4,
    // max 2*32=64 per byte, no carry), packed-u16 shuffle tree, lane0 -> global.
    const int wid = tid >> 6, lane = tid & 63;
    for (int q = 0; q < 8; ++q) {
        const int p  = wid * 8 + q;
        const int ch = p >> 4, w = p & 15;
        unsigned s = hist[ch][w][lane] + hist[ch][w][lane+64];
        unsigned lo = s & 0x00FF00FFu;            // bytes 0,2 in u16 slots
        unsigned hi = (s >> 8) & 0x00FF00FFu;     // bytes 1,3
        for (int o = 32; o > 0; o >>= 1) {
            lo += __shfl_down(lo, o);
            hi += __shfl_down(hi, o);
        }
        if (lane == 0) {
            const unsigned base = (unsigned)(b*2 + ch) * NB1 + (unsigned)w * 4u;
            unsigned c0 = lo & 0xFFFFu, c2 = lo >> 16;
            unsigned c1 = hi & 0xFFFFu, c3 = hi >> 16;
            if (c0) atomicAdd(&h1c[base+0], c0);
            if (c1) atomicAdd(&h1c[base+1], c1);
            if (c2) atomicAdd(&h1c[base+2], c2);
            if (c3) atomicAdd(&h1c[base+3], c3);
        }
    }

    for (int o = 32; o > 0; o >>= 1) {
        pc0 += __shfl_down(pc0, o); ps0 += __shfl_down(ps0, o);
        pc1 += __shfl_down(pc1, o); ps1 += __shfl_down(ps1, o);
    }
    if (lane == 0) { wpc[wid] = pc0; wps[wid] = ps0; wpc[4+wid] = pc1; wps[4+wid] = ps1; }
    __syncthreads();
    if (tid == 0) {
        unsigned t0 = 0, t1 = 0; float s0 = 0.f, s1 = 0.f;
        for (int q = 0; q < 4; ++q) { t0 += wpc[q]; s0 += wps[q]; t1 += wpc[4+q]; s1 += wps[4+q]; }
        atomicAdd(&pcnt[b*2+0], t0); unsafeAtomicAdd(&psum[b*2+0], s0);
        atomicAdd(&pcnt[b*2+1], t1); unsafeAtomicAdd(&psum[b*2+1], s1);
    }
}

// ---------------------------------------------------------------------------
// Block suffix select over an LDS histogram (NBINS multiple of 256).
// ---------------------------------------------------------------------------
template<int NBINS>
__device__ __forceinline__ void select_counts(
    const unsigned* cnt, unsigned k, unsigned& outBin, unsigned& outRem)
{
    constexpr int PER = NBINS / 256;
    const int t = threadIdx.x;
    unsigned lc[PER];
#pragma unroll
    for (int j = 0; j < PER; ++j) lc[j] = cnt[t*PER + j];
    unsigned lsum = 0;
#pragma unroll
    for (int j = 0; j < PER; ++j) lsum += lc[j];

    __shared__ unsigned part[256];
    __shared__ unsigned s_bin, s_rem;
    part[t] = lsum;
    __syncthreads();
    for (int off = 1; off < 256; off <<= 1) {
        unsigned v = (t + off < 256) ? part[t + off] : 0u;
        __syncthreads();
        part[t] += v;
        __syncthreads();
    }
    unsigned cum = (t + 1 < 256) ? part[t + 1] : 0u;
#pragma unroll
    for (int j = PER - 1; j >= 0; --j) {
        unsigned c = lc[j];
        if (cum < k && k <= cum + c) { s_bin = (unsigned)(t * PER + j); s_rem = k - cum; }
        cum += c;
    }
    __syncthreads();
    outBin = s_bin; outRem = s_rem;
}

// scan1: per channel -> k, posi, T1, rem1 (64-bin suffix scan, serial t0).
__global__ void k_scan1(
    const unsigned* __restrict__ h1c,
    const unsigned* __restrict__ pcnt, const float* __restrict__ psum,
    unsigned* __restrict__ T1, unsigned* __restrict__ rem1,
    unsigned* __restrict__ kk, float* __restrict__ posi)
{
    if (threadIdx.x != 0) return;
    const int idx = blockIdx.x;
    const unsigned p  = pcnt[idx];
    const unsigned nn = (unsigned)NPS - p;
    const unsigned k  = p ? ((nn < 3u*p) ? nn : 3u*p) : TOPK_NO_POS;
    kk[idx]   = k;
    posi[idx] = p ? (psum[idx] / (float)p) : 0.0f;
    if (k == 0u) { T1[idx] = 0xFFFFFFFFu; rem1[idx] = 0u; return; }
    unsigned cum = 0, bin = 0, rem = k;
    for (int j = NB1 - 1; j >= 0; --j) {
        const unsigned c = h1c[idx*NB1 + j];
        if (cum < k && k <= cum + c) { bin = (unsigned)j; rem = k - cum; }
        cum += c;
    }
    T1[idx] = bin; rem1[idx] = rem;
}

// ---------------------------------------------------------------------------
// Pass 2: register sum above T1 bin + LDS-staged compaction of T1-bin members.
// ---------------------------------------------------------------------------
__global__ __launch_bounds__(256, 8) void k_compact(
    const float4* __restrict__ pred4,
    const float4* __restrict__ reg4,
    const float4* __restrict__ aff4,
    const unsigned* __restrict__ T1,
    float* __restrict__ cbuf, unsigned* __restrict__ ccnt,
    double* __restrict__ sumAbove)
{
    __shared__ float    lb0[CAPB], lb1[CAPB];
    __shared__ unsigned lcnt[2];
    __shared__ unsigned sbase[2];
    __shared__ float    wred[8];
    if (threadIdx.x < 2) lcnt[threadIdx.x] = 0u;
    __syncthreads();

    const int b = blockIdx.y;
    const unsigned t1r = T1[b*2+0], t1a = T1[b*2+1];
    const int tid = threadIdx.x, lane = tid & 63;
    float*    gb0 = cbuf + (size_t)(b*2+0) * CAP;
    float*    gb1 = cbuf + (size_t)(b*2+1) * CAP;
    unsigned* gc0 = ccnt + b*2+0;
    unsigned* gc1 = ccnt + b*2+1;
    float rs0 = 0.f, rs1 = 0.f;

    auto proc = [&](float tgt, float pg, unsigned t1, float& rs,
                    unsigned* lcnt_p, float* lbuf, unsigned* gcnt, float* gbuf) {
        if (tgt >= POS_THR_F) return;            // positive pixel
        const float d = pg - tgt;
        const float v = d * d;
        const unsigned key = bin_of(v);
        if (key > t1) { rs += v; return; }
        if (key != t1) return;
        const unsigned ix = atomicAdd(lcnt_p, 1u);                 // LDS, few lanes
        if (ix < (unsigned)CAPB) lbuf[ix] = v;
        else { unsigned g = atomicAdd(gcnt, 1u); if (g < (unsigned)CAP) gbuf[g] = v; }
    };

    constexpr int ITERS = EPB / 1024;            // 4
    long idx4 = (((long)b * NPS + (long)blockIdx.x * EPB) >> 2) + tid;

    for (int i = 0; i < ITERS; ++i) {
        const float4 r  = reg4[idx4];
        const float4 a  = aff4[idx4];
        const float4 pA = pred4[idx4 * 2];
        const float4 pB = pred4[idx4 * 2 + 1];
        proc(r.x, pA.x, t1r, rs0, &lcnt[0], lb0, gc0, gb0);
        proc(r.y, pA.z, t1r, rs0, &lcnt[0], lb0, gc0, gb0);
        proc(r.z, pB.x, t1r, rs0, &lcnt[0], lb0, gc0, gb0);
        proc(r.w, pB.z, t1r, rs0, &lcnt[0], lb0, gc0, gb0);
        proc(a.x, pA.y, t1a, rs1, &lcnt[1], lb1, gc1, gb1);
        proc(a.y, pA.w, t1a, rs1, &lcnt[1], lb1, gc1, gb1);
        proc(a.z, pB.y, t1a, rs1, &lcnt[1], lb1, gc1, gb1);
        proc(a.w, pB.w, t1a, rs1, &lcnt[1], lb1, gc1, gb1);
        idx4 += 256;
    }
    __syncthreads();

    const unsigned lc0 = lcnt[0] < (unsigned)CAPB ? lcnt[0] : (unsigned)CAPB;
    const unsigned lc1 = lcnt[1] < (unsigned)CAPB ? lcnt[1] : (unsigned)CAPB;
    if (tid == 0)      sbase[0] = lc0 ? atomicAdd(gc0, lc0) : 0u;
    else if (tid == 1) sbase[1] = lc1 ? atomicAdd(gc1, lc1) : 0u;
    __syncthreads();
    for (unsigned i = tid; i < lc0; i += 256) {
        unsigned g = sbase[0] + i;
        if (g < (unsigned)CAP) gb0[g] = lb0[i];
    }
    for (unsigned i = tid; i < lc1; i += 256) {
        unsigned g = sbase[1] + i;
        if (g < (unsigned)CAP) gb1[g] = lb1[i];
    }
    for (int o = 32; o > 0; o >>= 1) { rs0 += __shfl_down(rs0, o); rs1 += __shfl_down(rs1, o); }
    const int wid = tid >> 6;
    if (lane == 0) { wred[wid] = rs0; wred[4+wid] = rs1; }
    __syncthreads();
    if (tid == 0) {
        float s0 = wred[0]+wred[1]+wred[2]+wred[3];
        float s1 = wred[4]+wred[5]+wred[6]+wred[7];
        unsafeAtomicAdd(&sumAbove[b*2+0], (double)s0);
        unsafeAtomicAdd(&sumAbove[b*2+1], (double)s1);
    }
}

// ---------------------------------------------------------------------------
// Refine: radix select over the compact buffer. When T1>0 all elements share
// bits[31:21] (= T1+RAW_OFF) so round A is skipped; otherwise (T1==0) a
// 512-bin round over bits[31:21] runs first. Then bits[20:10], bits[9:0].
// ---------------------------------------------------------------------------
__global__ __launch_bounds__(256) void k_refine(
    const float* __restrict__ cbuf, const unsigned* __restrict__ ccnt,
    const unsigned* __restrict__ T1, const unsigned* __restrict__ rem1,
    const unsigned* __restrict__ kk, const float* __restrict__ posi,
    const double* __restrict__ sumAbove,
    float* __restrict__ contrib)
{
    const int ch = blockIdx.x;
    const unsigned k = kk[ch];
    if (k == 0u) {
        if (threadIdx.x == 0) contrib[ch] = posi[ch];
        return;
    }
    unsigned cnt = ccnt[ch];
    if (cnt > (unsigned)CAP) cnt = (unsigned)CAP;
    const float* buf = cbuf + (size_t)ch * CAP;
    const int tid = threadIdx.x;

    __shared__ unsigned h[2048];
    __shared__ double   wsum[4];

    unsigned TA, remA;
    const unsigned t1 = T1[ch];
    if (t1 > 0u) {
        TA = t1 + (unsigned)RAW_OFF;             // all elements share top bits
        remA = rem1[ch];
    } else {
        // Round A: bits[31:21] over raws 0..RAW_OFF (512 bins suffice)
        for (int j = tid; j < 512; j += 256) h[j] = 0u;
        __syncthreads();
        for (unsigned i = tid; i < cnt; i += 256)
            atomicAdd(&h[__float_as_uint(buf[i]) >> 21], 1u);
        __syncthreads();
        select_counts<512>(h, rem1[ch], TA, remA);
        __syncthreads();
    }

    // Round B: bits[20:10] among TA members (2048 bins)
    for (int j = tid; j < 2048; j += 256) h[j] = 0u;
    __syncthreads();
    for (unsigned i = tid; i < cnt; i += 256) {
        const unsigned bt = __float_as_uint(buf[i]);
        if ((bt >> 21) == TA) atomicAdd(&h[(bt >> 10) & 2047u], 1u);
    }
    __syncthreads();
    unsigned TB, remB;
    select_counts<2048>(h, remA, TB, remB);
    __syncthreads();

    // Round C: bits[9:0] among TA:TB members (1024 bins)
    for (int j = tid; j < 1024; j += 256) h[j] = 0u;
    __syncthreads();
    const unsigned abPrefix = (TA << 11) | TB;
    for (unsigned i = tid; i < cnt; i += 256) {
        const unsigned bt = __float_as_uint(buf[i]);
        if ((bt >> 10) == abPrefix) atomicAdd(&h[bt & 1023u], 1u);
    }
    __syncthreads();
    unsigned TC, rem3;
    select_counts<1024>(h, remB, TC, rem3);

    const float t = __uint_as_float((TA << 21) | (TB << 10) | TC);
    double s = 0.0;
    for (unsigned i = tid; i < cnt; i += 256) {
        const float v = buf[i];
        if (v > t) s += (double)v;
    }
    for (int o = 32; o > 0; o >>= 1) s += __shfl_down(s, o);
    const int wid = tid >> 6, lane = tid & 63;
    if (lane == 0) wsum[wid] = s;
    __syncthreads();
    if (tid == 0) {
        const double stop = wsum[0] + wsum[1] + wsum[2] + wsum[3];
        const double nega = (sumAbove[ch] + stop + (double)rem3 * (double)t) / (double)k;
        contrib[ch] = (float)((double)posi[ch] + nega);
    }
}

__global__ void k_reduce(const float* __restrict__ contrib, float* __restrict__ out)
{
    double v = (double)contrib[threadIdx.x];
    for (int o = 32; o > 0; o >>= 1) v += __shfl_down(v, o);
    if (threadIdx.x == 0) out[0] = (float)(v / (double)BATCH);
}

// ---------------------------------------------------------------------------
extern "C" void kernel_launch(void* const* d_in, const int* in_sizes, int n_in,
                              void* d_out, int out_size, void* d_ws, size_t ws_size,
                              hipStream_t stream)
{
    (void)in_sizes; (void)n_in; (void)out_size; (void)ws_size;
    const float4* pred4 = (const float4*)d_in[0];
    const float4* reg4  = (const float4*)d_in[1];
    const float4* aff4  = (const float4*)d_in[2];

    char* w = (char*)d_ws;
    unsigned* h1c  = (unsigned*)w;                        // 64*64 u32 = 16 KB
    unsigned* pcnt = h1c + (size_t)CH2 * NB1;
    float*    psum = (float*)(pcnt + CH2);
    unsigned* T1   = (unsigned*)(psum + CH2);
    unsigned* rem1 = T1 + CH2;
    unsigned* kk   = rem1 + CH2;
    float*    posi = (float*)(kk + CH2);
    float*    contrib = posi + CH2;
    unsigned* ccnt = (unsigned*)(contrib + CH2);
    double*   sumAbove = (double*)(ccnt + CH2);           // offset divisible by 8
    const size_t hdr_bytes = (size_t)((char*)(sumAbove + CH2) - w);  // ~19 KB

    float* cbuf = (float*)(w + ((size_t)1 << 20));        // 33.5 MB at +1 MB

    hipMemsetAsync(d_ws, 0, hdr_bytes, stream);

    dim3 grid(BX, BATCH);
    k_hist<<<grid, 256, 0, stream>>>(pred4, reg4, aff4, h1c, pcnt, psum);
    k_scan1<<<CH2, 64, 0, stream>>>(h1c, pcnt, psum, T1, rem1, kk, posi);
    k_compact<<<grid, 256, 0, stream>>>(pred4, reg4, aff4, T1, cbuf, ccnt, sumAbove);
    k_refine<<<CH2, 256, 0, stream>>>(cbuf, ccnt, T1, rem1, kk, posi, sumAbove, contrib);
    k_reduce<<<1, 64, 0, stream>>>(contrib, (float*)d_out);
}

// Round 5
// 401.599 us; speedup vs baseline: 1.3311x; 1.3311x over previous
//
#include <hip/hip_runtime.h>

// CRAFT OHEM loss, round 9.
// R7/R8 post-mortem: both theory-driven k_hist rewrites (private histograms,
// occupancy pushes) REGRESSED vs the round-5 baseline (397 us). Occupancy
// (36/66/71%) does not predict dur; conflicts (2.74M cyc aggregate ~ 4.5 us/CU)
// were never the bottleneck. R9 reverts the full pipeline to the measured-best
// R5 structure (prefetch, EPB 16384, 2048-bin shared histogram) and adds one
// low-risk win: k_reduce folded into k_refine via a done-counter (last block
// reduces), removing one kernel launch.

constexpr int   BATCH   = 32;
constexpr int   NPS     = 768 * 768;            // 589824
constexpr int   CH2     = BATCH * 2;            // 64
constexpr int   EPB     = 16384;                // pixels per block
constexpr int   BX      = NPS / EPB;            // 36
constexpr float POS_THR_F = 0.1f;
constexpr unsigned TOPK_NO_POS = 500u;
constexpr int   NB1     = 2048;                 // stage-1 bins: bits>>19
constexpr int   CAP     = 131072;               // global compact buffer per channel
constexpr int   CAPB    = 1024;                 // LDS staging per channel per block

// ---------------------------------------------------------------------------
// Pass 1: counts-only 2048-bin histogram per channel + positive stats.
// ---------------------------------------------------------------------------
__global__ __launch_bounds__(256, 6) void k_hist(
    const float4* __restrict__ pred4,
    const float4* __restrict__ reg4,
    const float4* __restrict__ aff4,
    unsigned* __restrict__ h1c,
    unsigned* __restrict__ pcnt, float* __restrict__ psum)
{
    __shared__ unsigned sc0[NB1], sc1[NB1];
    __shared__ unsigned wpc[8];
    __shared__ float    wps[8];
    for (int j = threadIdx.x; j < NB1; j += 256) { sc0[j] = 0u; sc1[j] = 0u; }
    __syncthreads();

    const int  b   = blockIdx.y;
    const int  tid = threadIdx.x;
    constexpr int ITERS = EPB / 1024;            // 16
    long idx4 = (((long)b * NPS + (long)blockIdx.x * EPB) >> 2) + tid;

    unsigned pc0 = 0, pc1 = 0;
    float    ps0 = 0.f, ps1 = 0.f;

    float4 r = reg4[idx4], a = aff4[idx4];
    float4 pA = pred4[idx4 * 2], pB = pred4[idx4 * 2 + 1];

    for (int i = 0; i < ITERS; ++i) {
        float4 rn, an, pAn, pBn;
        if (i + 1 < ITERS) {
            const long nx = idx4 + 256;
            rn = reg4[nx]; an = aff4[nx]; pAn = pred4[nx * 2]; pBn = pred4[nx * 2 + 1];
        }
#define DO_PIX(RR, AA, PG, PA) do {                                           \
        float d0 = (PG) - (RR); float v0 = d0 * d0;                           \
        if ((RR) >= POS_THR_F) { pc0++; ps0 += v0; }                          \
        else atomicAdd(&sc0[__float_as_uint(v0) >> 19], 1u);                  \
        float d1 = (PA) - (AA); float v1 = d1 * d1;                           \
        if ((AA) >= POS_THR_F) { pc1++; ps1 += v1; }                          \
        else atomicAdd(&sc1[__float_as_uint(v1) >> 19], 1u);                  \
    } while (0)
        DO_PIX(r.x, a.x, pA.x, pA.y);
        DO_PIX(r.y, a.y, pA.z, pA.w);
        DO_PIX(r.z, a.z, pB.x, pB.y);
        DO_PIX(r.w, a.w, pB.z, pB.w);
#undef DO_PIX
        idx4 += 256; r = rn; a = an; pA = pAn; pB = pBn;
    }
    __syncthreads();

    for (int j = tid; j < NB1; j += 256) {
        unsigned c0 = sc0[j];
        if (c0) atomicAdd(&h1c[(b*2+0)*NB1 + j], c0);
        unsigned c1 = sc1[j];
        if (c1) atomicAdd(&h1c[(b*2+1)*NB1 + j], c1);
    }
    for (int o = 32; o > 0; o >>= 1) {
        pc0 += __shfl_down(pc0, o); ps0 += __shfl_down(ps0, o);
        pc1 += __shfl_down(pc1, o); ps1 += __shfl_down(ps1, o);
    }
    const int wid = tid >> 6, lane = tid & 63;
    if (lane == 0) { wpc[wid] = pc0; wps[wid] = ps0; wpc[4+wid] = pc1; wps[4+wid] = ps1; }
    __syncthreads();
    if (tid == 0) {
        unsigned t0 = 0, t1 = 0; float s0 = 0.f, s1 = 0.f;
        for (int q = 0; q < 4; ++q) { t0 += wpc[q]; s0 += wps[q]; t1 += wpc[4+q]; s1 += wps[4+q]; }
        atomicAdd(&pcnt[b*2+0], t0); unsafeAtomicAdd(&psum[b*2+0], s0);
        atomicAdd(&pcnt[b*2+1], t1); unsafeAtomicAdd(&psum[b*2+1], s1);
    }
}

// ---------------------------------------------------------------------------
// Block suffix select (counts only; works on LDS or global pointers).
// ---------------------------------------------------------------------------
template<int NBINS>
__device__ __forceinline__ void select_counts(
    const unsigned* cnt, unsigned k, unsigned& outBin, unsigned& outRem)
{
    constexpr int PER = NBINS / 256;
    const int t = threadIdx.x;
    unsigned lc[PER];
#pragma unroll
    for (int j = 0; j < PER; ++j) lc[j] = cnt[t*PER + j];
    unsigned lsum = 0;
#pragma unroll
    for (int j = 0; j < PER; ++j) lsum += lc[j];

    __shared__ unsigned part[256];
    __shared__ unsigned s_bin, s_rem;
    part[t] = lsum;
    __syncthreads();
    for (int off = 1; off < 256; off <<= 1) {
        unsigned v = (t + off < 256) ? part[t + off] : 0u;
        __syncthreads();
        part[t] += v;
        __syncthreads();
    }
    unsigned cum = (t + 1 < 256) ? part[t + 1] : 0u;
#pragma unroll
    for (int j = PER - 1; j >= 0; --j) {
        unsigned c = lc[j];
        if (cum < k && k <= cum + c) { s_bin = (unsigned)(t * PER + j); s_rem = k - cum; }
        cum += c;
    }
    __syncthreads();
    outBin = s_bin; outRem = s_rem;
}

// scan1: per channel -> k, posi, T1, rem1
__global__ __launch_bounds__(256) void k_scan1(
    const unsigned* __restrict__ h1c,
    const unsigned* __restrict__ pcnt, const float* __restrict__ psum,
    unsigned* __restrict__ T1, unsigned* __restrict__ rem1,
    unsigned* __restrict__ kk, float* __restrict__ posi)
{
    const int idx = blockIdx.x;
    const unsigned p  = pcnt[idx];
    const unsigned nn = (unsigned)NPS - p;
    const unsigned k  = p ? ((nn < 3u*p) ? nn : 3u*p) : TOPK_NO_POS;
    if (threadIdx.x == 0) {
        kk[idx]   = k;
        posi[idx] = p ? (psum[idx] / (float)p) : 0.0f;
    }
    if (k == 0u) {
        if (threadIdx.x == 0) { T1[idx] = 0xFFFFFFFFu; rem1[idx] = 0u; }
        return;
    }
    unsigned bin, rem;
    select_counts<NB1>(h1c + idx*NB1, k, bin, rem);
    if (threadIdx.x == 0) { T1[idx] = bin; rem1[idx] = rem; }
}

// ---------------------------------------------------------------------------
// Pass 2: register sum of elements strictly above the T1 bin (f32 -> f64 block
// atomic) + LDS-staged compaction of T1-bin members.
// ---------------------------------------------------------------------------
__global__ __launch_bounds__(256, 6) void k_compact(
    const float4* __restrict__ pred4,
    const float4* __restrict__ reg4,
    const float4* __restrict__ aff4,
    const unsigned* __restrict__ T1,
    float* __restrict__ cbuf, unsigned* __restrict__ ccnt,
    double* __restrict__ sumAbove)
{
    __shared__ float    lb0[CAPB], lb1[CAPB];
    __shared__ unsigned lcnt[2];
    __shared__ unsigned sbase[2];
    __shared__ float    wred[8];
    if (threadIdx.x < 2) lcnt[threadIdx.x] = 0u;
    __syncthreads();

    const int b = blockIdx.y;
    const unsigned t1r = T1[b*2+0], t1a = T1[b*2+1];
    const int tid = threadIdx.x, lane = tid & 63;
    float*    gb0 = cbuf + (size_t)(b*2+0) * CAP;
    float*    gb1 = cbuf + (size_t)(b*2+1) * CAP;
    unsigned* gc0 = ccnt + b*2+0;
    unsigned* gc1 = ccnt + b*2+1;
    float rs0 = 0.f, rs1 = 0.f;

    auto proc = [&](float tgt, float pg, unsigned t1, float& rs,
                    unsigned* lcnt_p, float* lbuf, unsigned* gcnt, float* gbuf) {
        if (tgt >= POS_THR_F) return;            // positive pixel
        const float d = pg - tgt;
        const float v = d * d;
        const unsigned key = __float_as_uint(v) >> 19;
        if (key > t1) { rs += v; return; }
        if (key != t1) return;
        const unsigned long long m = __ballot(true);
        const int ldr = __ffsll(m) - 1;
        const unsigned pre = (unsigned)__popcll(m & ((1ull << lane) - 1ull));
        unsigned base = 0;
        if (lane == ldr) base = atomicAdd(lcnt_p, (unsigned)__popcll(m));  // LDS
        base = __shfl(base, ldr);
        const unsigned ix = base + pre;
        if (ix < (unsigned)CAPB) lbuf[ix] = v;
        else { unsigned g = atomicAdd(gcnt, 1u); if (g < (unsigned)CAP) gbuf[g] = v; }
    };

    constexpr int ITERS = EPB / 1024;            // 16
    long idx4 = (((long)b * NPS + (long)blockIdx.x * EPB) >> 2) + tid;

    float4 r = reg4[idx4], a = aff4[idx4];
    float4 pA = pred4[idx4 * 2], pB = pred4[idx4 * 2 + 1];

    for (int i = 0; i < ITERS; ++i) {
        float4 rn, an, pAn, pBn;
        if (i + 1 < ITERS) {
            const long nx = idx4 + 256;
            rn = reg4[nx]; an = aff4[nx]; pAn = pred4[nx * 2]; pBn = pred4[nx * 2 + 1];
        }
        proc(r.x, pA.x, t1r, rs0, &lcnt[0], lb0, gc0, gb0);
        proc(r.y, pA.z, t1r, rs0, &lcnt[0], lb0, gc0, gb0);
        proc(r.z, pB.x, t1r, rs0, &lcnt[0], lb0, gc0, gb0);
        proc(r.w, pB.z, t1r, rs0, &lcnt[0], lb0, gc0, gb0);
        proc(a.x, pA.y, t1a, rs1, &lcnt[1], lb1, gc1, gb1);
        proc(a.y, pA.w, t1a, rs1, &lcnt[1], lb1, gc1, gb1);
        proc(a.z, pB.y, t1a, rs1, &lcnt[1], lb1, gc1, gb1);
        proc(a.w, pB.w, t1a, rs1, &lcnt[1], lb1, gc1, gb1);
        idx4 += 256; r = rn; a = an; pA = pAn; pB = pBn;
    }
    __syncthreads();

    const unsigned lc0 = lcnt[0] < (unsigned)CAPB ? lcnt[0] : (unsigned)CAPB;
    const unsigned lc1 = lcnt[1] < (unsigned)CAPB ? lcnt[1] : (unsigned)CAPB;
    if (tid == 0)      sbase[0] = lc0 ? atomicAdd(gc0, lc0) : 0u;
    else if (tid == 1) sbase[1] = lc1 ? atomicAdd(gc1, lc1) : 0u;
    __syncthreads();
    for (unsigned i = tid; i < lc0; i += 256) {
        unsigned g = sbase[0] + i;
        if (g < (unsigned)CAP) gb0[g] = lb0[i];
    }
    for (unsigned i = tid; i < lc1; i += 256) {
        unsigned g = sbase[1] + i;
        if (g < (unsigned)CAP) gb1[g] = lb1[i];
    }
    for (int o = 32; o > 0; o >>= 1) { rs0 += __shfl_down(rs0, o); rs1 += __shfl_down(rs1, o); }
    const int wid = tid >> 6;
    if (lane == 0) { wred[wid] = rs0; wred[4+wid] = rs1; }
    __syncthreads();
    if (tid == 0) {
        float s0 = wred[0]+wred[1]+wred[2]+wred[3];
        float s1 = wred[4]+wred[5]+wred[6]+wred[7];
        unsafeAtomicAdd(&sumAbove[b*2+0], (double)s0);
        unsafeAtomicAdd(&sumAbove[b*2+1], (double)s1);
    }
}

// ---------------------------------------------------------------------------
// Refine: per channel, two in-LDS histogram rounds over the compact buffer
// (bits[18:8] then bits[7:0]), exact threshold, f64 sum above it.
// Last block (done-counter) also performs the final 64-channel reduction,
// replacing the k_reduce launch.
// ---------------------------------------------------------------------------
__global__ __launch_bounds__(256) void k_refine(
    const float* __restrict__ cbuf, const unsigned* __restrict__ ccnt,
    const unsigned* __restrict__ T1, const unsigned* __restrict__ rem1,
    const unsigned* __restrict__ kk, const float* __restrict__ posi,
    const double* __restrict__ sumAbove,
    float* __restrict__ contrib,
    unsigned* __restrict__ done, float* __restrict__ out)
{
    const int ch = blockIdx.x;
    const int tid = threadIdx.x;
    const unsigned k = kk[ch];

    auto finish = [&](float cval) {
        // tid == 0 only
        contrib[ch] = cval;
        __threadfence();
        const unsigned d = atomicAdd(done, 1u);
        if (d == (unsigned)CH2 - 1u) {          // last channel done -> reduce
            __threadfence();
            double acc = 0.0;
            for (int i = 0; i < CH2; ++i) acc += (double)contrib[i];
            out[0] = (float)(acc / (double)BATCH);
        }
    };

    if (k == 0u) {
        if (tid == 0) finish(posi[ch]);
        return;
    }
    unsigned cnt = ccnt[ch];
    if (cnt > (unsigned)CAP) cnt = (unsigned)CAP;
    const float* buf = cbuf + (size_t)ch * CAP;

    __shared__ unsigned hA[NB1];
    __shared__ unsigned hB[256];
    __shared__ double   wsum[4];
    for (int j = tid; j < NB1; j += 256) hA[j] = 0u;
    __syncthreads();
    for (unsigned i = tid; i < cnt; i += 256) {
        const unsigned bt = __float_as_uint(buf[i]);
        atomicAdd(&hA[(bt >> 8) & 2047u], 1u);
    }
    __syncthreads();
    unsigned T2, rem2;
    select_counts<NB1>(hA, rem1[ch], T2, rem2);

    hB[tid] = 0u;
    __syncthreads();
    for (unsigned i = tid; i < cnt; i += 256) {
        const unsigned bt = __float_as_uint(buf[i]);
        if (((bt >> 8) & 2047u) == T2) atomicAdd(&hB[bt & 255u], 1u);
    }
    __syncthreads();
    unsigned T3, rem3;
    select_counts<256>(hB, rem2, T3, rem3);

    const float t = __uint_as_float((T1[ch] << 19) | (T2 << 8) | T3);
    double s = 0.0;
    for (unsigned i = tid; i < cnt; i += 256) {
        const float v = buf[i];
        if (v > t) s += (double)v;
    }
    for (int o = 32; o > 0; o >>= 1) s += __shfl_down(s, o);
    const int wid = tid >> 6, lane = tid & 63;
    if (lane == 0) wsum[wid] = s;
    __syncthreads();
    if (tid == 0) {
        const double stop = wsum[0] + wsum[1] + wsum[2] + wsum[3];
        const double nega = (sumAbove[ch] + stop + (double)rem3 * (double)t) / (double)k;
        finish((float)((double)posi[ch] + nega));
    }
}

// ---------------------------------------------------------------------------
extern "C" void kernel_launch(void* const* d_in, const int* in_sizes, int n_in,
                              void* d_out, int out_size, void* d_ws, size_t ws_size,
                              hipStream_t stream)
{
    (void)in_sizes; (void)n_in; (void)out_size; (void)ws_size;
    const float4* pred4 = (const float4*)d_in[0];
    const float4* reg4  = (const float4*)d_in[1];
    const float4* aff4  = (const float4*)d_in[2];

    char* w = (char*)d_ws;
    unsigned* h1c  = (unsigned*)w;                        // 64*2048 u32 = 512 KB
    unsigned* pcnt = h1c + (size_t)CH2 * NB1;
    float*    psum = (float*)(pcnt + CH2);
    unsigned* T1   = (unsigned*)(psum + CH2);
    unsigned* rem1 = T1 + CH2;
    unsigned* kk   = rem1 + CH2;
    float*    posi = (float*)(kk + CH2);
    float*    contrib = posi + CH2;
    unsigned* ccnt = (unsigned*)(contrib + CH2);
    double*   sumAbove = (double*)(ccnt + CH2);           // offset divisible by 8
    unsigned* done = (unsigned*)(sumAbove + CH2);
    const size_t hdr_bytes = (size_t)((char*)(done + 1) - w);  // ~527 KB

    float* cbuf = (float*)(w + ((size_t)1 << 20));        // 33.5 MB at +1 MB

    hipMemsetAsync(d_ws, 0, hdr_bytes, stream);

    dim3 grid(BX, BATCH);
    k_hist<<<grid, 256, 0, stream>>>(pred4, reg4, aff4, h1c, pcnt, psum);
    k_scan1<<<CH2, 256, 0, stream>>>(h1c, pcnt, psum, T1, rem1, kk, posi);
    k_compact<<<grid, 256, 0, stream>>>(pred4, reg4, aff4, T1, cbuf, ccnt, sumAbove);
    k_refine<<<CH2, 256, 0, stream>>>(cbuf, ccnt, T1, rem1, kk, posi, sumAbove,
                                      contrib, done, (float*)d_out);
}

// Round 6
// 400.642 us; speedup vs baseline: 1.3343x; 1.0024x over previous
//
#include <hip/hip_runtime.h>

// CRAFT OHEM loss, round 10.
// R9 post-mortem: total back to 401 us (k_reduce fold neutral -> launches are
// not the cost). k_hist counters: VALU 7.8%, HBM 17%, LDS-atomic cycles
// bounded small, occupancy GRID-limited (4.5 blocks/CU). The residual must be
// exposed load latency. Evidence: R6 (0-deep) == R9 (1-deep prefetch) at
// ~115 us -- the compiler already hoists loads, so the pipe was never
// deepened. R10: true 2-deep software prefetch in k_hist and k_compact
// (8 float4 in flight/wave, 2 compute phases to hide latency). Everything
// else frozen at the R9 measured-best structure.

constexpr int   BATCH   = 32;
constexpr int   NPS     = 768 * 768;            // 589824
constexpr int   CH2     = BATCH * 2;            // 64
constexpr int   EPB     = 16384;                // pixels per block
constexpr int   BX      = NPS / EPB;            // 36
constexpr float POS_THR_F = 0.1f;
constexpr unsigned TOPK_NO_POS = 500u;
constexpr int   NB1     = 2048;                 // stage-1 bins: bits>>19
constexpr int   CAP     = 131072;               // global compact buffer per channel
constexpr int   CAPB    = 1024;                 // LDS staging per channel per block

// ---------------------------------------------------------------------------
// Pass 1: counts-only 2048-bin histogram per channel + positive stats.
// ---------------------------------------------------------------------------
__global__ __launch_bounds__(256, 6) void k_hist(
    const float4* __restrict__ pred4,
    const float4* __restrict__ reg4,
    const float4* __restrict__ aff4,
    unsigned* __restrict__ h1c,
    unsigned* __restrict__ pcnt, float* __restrict__ psum)
{
    __shared__ unsigned sc0[NB1], sc1[NB1];
    __shared__ unsigned wpc[8];
    __shared__ float    wps[8];
    for (int j = threadIdx.x; j < NB1; j += 256) { sc0[j] = 0u; sc1[j] = 0u; }
    __syncthreads();

    const int  b   = blockIdx.y;
    const int  tid = threadIdx.x;
    constexpr int ITERS = EPB / 1024;            // 16
    long idx4 = (((long)b * NPS + (long)blockIdx.x * EPB) >> 2) + tid;

    unsigned pc0 = 0, pc1 = 0;
    float    ps0 = 0.f, ps1 = 0.f;

    // 2-deep prefetch pipeline
    float4 r0 = reg4[idx4],          a0 = aff4[idx4];
    float4 pA0 = pred4[idx4 * 2],    pB0 = pred4[idx4 * 2 + 1];
    const long nx1 = idx4 + 256;
    float4 r1 = reg4[nx1],           a1 = aff4[nx1];
    float4 pA1 = pred4[nx1 * 2],     pB1 = pred4[nx1 * 2 + 1];

    for (int i = 0; i < ITERS; ++i) {
        float4 rn, an, pAn, pBn;
        if (i + 2 < ITERS) {
            const long nx = idx4 + 512;
            rn = reg4[nx]; an = aff4[nx]; pAn = pred4[nx * 2]; pBn = pred4[nx * 2 + 1];
        }
#define DO_PIX(RR, AA, PG, PA) do {                                           \
        float d0 = (PG) - (RR); float v0 = d0 * d0;                           \
        if ((RR) >= POS_THR_F) { pc0++; ps0 += v0; }                          \
        else atomicAdd(&sc0[__float_as_uint(v0) >> 19], 1u);                  \
        float d1 = (PA) - (AA); float v1 = d1 * d1;                           \
        if ((AA) >= POS_THR_F) { pc1++; ps1 += v1; }                          \
        else atomicAdd(&sc1[__float_as_uint(v1) >> 19], 1u);                  \
    } while (0)
        DO_PIX(r0.x, a0.x, pA0.x, pA0.y);
        DO_PIX(r0.y, a0.y, pA0.z, pA0.w);
        DO_PIX(r0.z, a0.z, pB0.x, pB0.y);
        DO_PIX(r0.w, a0.w, pB0.z, pB0.w);
#undef DO_PIX
        idx4 += 256;
        r0 = r1; a0 = a1; pA0 = pA1; pB0 = pB1;
        r1 = rn; a1 = an; pA1 = pAn; pB1 = pBn;
    }
    __syncthreads();

    for (int j = tid; j < NB1; j += 256) {
        unsigned c0 = sc0[j];
        if (c0) atomicAdd(&h1c[(b*2+0)*NB1 + j], c0);
        unsigned c1 = sc1[j];
        if (c1) atomicAdd(&h1c[(b*2+1)*NB1 + j], c1);
    }
    for (int o = 32; o > 0; o >>= 1) {
        pc0 += __shfl_down(pc0, o); ps0 += __shfl_down(ps0, o);
        pc1 += __shfl_down(pc1, o); ps1 += __shfl_down(ps1, o);
    }
    const int wid = tid >> 6, lane = tid & 63;
    if (lane == 0) { wpc[wid] = pc0; wps[wid] = ps0; wpc[4+wid] = pc1; wps[4+wid] = ps1; }
    __syncthreads();
    if (tid == 0) {
        unsigned t0 = 0, t1 = 0; float s0 = 0.f, s1 = 0.f;
        for (int q = 0; q < 4; ++q) { t0 += wpc[q]; s0 += wps[q]; t1 += wpc[4+q]; s1 += wps[4+q]; }
        atomicAdd(&pcnt[b*2+0], t0); unsafeAtomicAdd(&psum[b*2+0], s0);
        atomicAdd(&pcnt[b*2+1], t1); unsafeAtomicAdd(&psum[b*2+1], s1);
    }
}

// ---------------------------------------------------------------------------
// Block suffix select (counts only; works on LDS or global pointers).
// ---------------------------------------------------------------------------
template<int NBINS>
__device__ __forceinline__ void select_counts(
    const unsigned* cnt, unsigned k, unsigned& outBin, unsigned& outRem)
{
    constexpr int PER = NBINS / 256;
    const int t = threadIdx.x;
    unsigned lc[PER];
#pragma unroll
    for (int j = 0; j < PER; ++j) lc[j] = cnt[t*PER + j];
    unsigned lsum = 0;
#pragma unroll
    for (int j = 0; j < PER; ++j) lsum += lc[j];

    __shared__ unsigned part[256];
    __shared__ unsigned s_bin, s_rem;
    part[t] = lsum;
    __syncthreads();
    for (int off = 1; off < 256; off <<= 1) {
        unsigned v = (t + off < 256) ? part[t + off] : 0u;
        __syncthreads();
        part[t] += v;
        __syncthreads();
    }
    unsigned cum = (t + 1 < 256) ? part[t + 1] : 0u;
#pragma unroll
    for (int j = PER - 1; j >= 0; --j) {
        unsigned c = lc[j];
        if (cum < k && k <= cum + c) { s_bin = (unsigned)(t * PER + j); s_rem = k - cum; }
        cum += c;
    }
    __syncthreads();
    outBin = s_bin; outRem = s_rem;
}

// scan1: per channel -> k, posi, T1, rem1
__global__ __launch_bounds__(256) void k_scan1(
    const unsigned* __restrict__ h1c,
    const unsigned* __restrict__ pcnt, const float* __restrict__ psum,
    unsigned* __restrict__ T1, unsigned* __restrict__ rem1,
    unsigned* __restrict__ kk, float* __restrict__ posi)
{
    const int idx = blockIdx.x;
    const unsigned p  = pcnt[idx];
    const unsigned nn = (unsigned)NPS - p;
    const unsigned k  = p ? ((nn < 3u*p) ? nn : 3u*p) : TOPK_NO_POS;
    if (threadIdx.x == 0) {
        kk[idx]   = k;
        posi[idx] = p ? (psum[idx] / (float)p) : 0.0f;
    }
    if (k == 0u) {
        if (threadIdx.x == 0) { T1[idx] = 0xFFFFFFFFu; rem1[idx] = 0u; }
        return;
    }
    unsigned bin, rem;
    select_counts<NB1>(h1c + idx*NB1, k, bin, rem);
    if (threadIdx.x == 0) { T1[idx] = bin; rem1[idx] = rem; }
}

// ---------------------------------------------------------------------------
// Pass 2: register sum of elements strictly above the T1 bin (f32 -> f64 block
// atomic) + LDS-staged compaction of T1-bin members.
// ---------------------------------------------------------------------------
__global__ __launch_bounds__(256, 6) void k_compact(
    const float4* __restrict__ pred4,
    const float4* __restrict__ reg4,
    const float4* __restrict__ aff4,
    const unsigned* __restrict__ T1,
    float* __restrict__ cbuf, unsigned* __restrict__ ccnt,
    double* __restrict__ sumAbove)
{
    __shared__ float    lb0[CAPB], lb1[CAPB];
    __shared__ unsigned lcnt[2];
    __shared__ unsigned sbase[2];
    __shared__ float    wred[8];
    if (threadIdx.x < 2) lcnt[threadIdx.x] = 0u;
    __syncthreads();

    const int b = blockIdx.y;
    const unsigned t1r = T1[b*2+0], t1a = T1[b*2+1];
    const int tid = threadIdx.x, lane = tid & 63;
    float*    gb0 = cbuf + (size_t)(b*2+0) * CAP;
    float*    gb1 = cbuf + (size_t)(b*2+1) * CAP;
    unsigned* gc0 = ccnt + b*2+0;
    unsigned* gc1 = ccnt + b*2+1;
    float rs0 = 0.f, rs1 = 0.f;

    auto proc = [&](float tgt, float pg, unsigned t1, float& rs,
                    unsigned* lcnt_p, float* lbuf, unsigned* gcnt, float* gbuf) {
        if (tgt >= POS_THR_F) return;            // positive pixel
        const float d = pg - tgt;
        const float v = d * d;
        const unsigned key = __float_as_uint(v) >> 19;
        if (key > t1) { rs += v; return; }
        if (key != t1) return;
        const unsigned long long m = __ballot(true);
        const int ldr = __ffsll(m) - 1;
        const unsigned pre = (unsigned)__popcll(m & ((1ull << lane) - 1ull));
        unsigned base = 0;
        if (lane == ldr) base = atomicAdd(lcnt_p, (unsigned)__popcll(m));  // LDS
        base = __shfl(base, ldr);
        const unsigned ix = base + pre;
        if (ix < (unsigned)CAPB) lbuf[ix] = v;
        else { unsigned g = atomicAdd(gcnt, 1u); if (g < (unsigned)CAP) gbuf[g] = v; }
    };

    constexpr int ITERS = EPB / 1024;            // 16
    long idx4 = (((long)b * NPS + (long)blockIdx.x * EPB) >> 2) + tid;

    // 2-deep prefetch pipeline
    float4 r0 = reg4[idx4],          a0 = aff4[idx4];
    float4 pA0 = pred4[idx4 * 2],    pB0 = pred4[idx4 * 2 + 1];
    const long nx1 = idx4 + 256;
    float4 r1 = reg4[nx1],           a1 = aff4[nx1];
    float4 pA1 = pred4[nx1 * 2],     pB1 = pred4[nx1 * 2 + 1];

    for (int i = 0; i < ITERS; ++i) {
        float4 rn, an, pAn, pBn;
        if (i + 2 < ITERS) {
            const long nx = idx4 + 512;
            rn = reg4[nx]; an = aff4[nx]; pAn = pred4[nx * 2]; pBn = pred4[nx * 2 + 1];
        }
        proc(r0.x, pA0.x, t1r, rs0, &lcnt[0], lb0, gc0, gb0);
        proc(r0.y, pA0.z, t1r, rs0, &lcnt[0], lb0, gc0, gb0);
        proc(r0.z, pB0.x, t1r, rs0, &lcnt[0], lb0, gc0, gb0);
        proc(r0.w, pB0.z, t1r, rs0, &lcnt[0], lb0, gc0, gb0);
        proc(a0.x, pA0.y, t1a, rs1, &lcnt[1], lb1, gc1, gb1);
        proc(a0.y, pA0.w, t1a, rs1, &lcnt[1], lb1, gc1, gb1);
        proc(a0.z, pB0.y, t1a, rs1, &lcnt[1], lb1, gc1, gb1);
        proc(a0.w, pB0.w, t1a, rs1, &lcnt[1], lb1, gc1, gb1);
        idx4 += 256;
        r0 = r1; a0 = a1; pA0 = pA1; pB0 = pB1;
        r1 = rn; a1 = an; pA1 = pAn; pB1 = pBn;
    }
    __syncthreads();

    const unsigned lc0 = lcnt[0] < (unsigned)CAPB ? lcnt[0] : (unsigned)CAPB;
    const unsigned lc1 = lcnt[1] < (unsigned)CAPB ? lcnt[1] : (unsigned)CAPB;
    if (tid == 0)      sbase[0] = lc0 ? atomicAdd(gc0, lc0) : 0u;
    else if (tid == 1) sbase[1] = lc1 ? atomicAdd(gc1, lc1) : 0u;
    __syncthreads();
    for (unsigned i = tid; i < lc0; i += 256) {
        unsigned g = sbase[0] + i;
        if (g < (unsigned)CAP) gb0[g] = lb0[i];
    }
    for (unsigned i = tid; i < lc1; i += 256) {
        unsigned g = sbase[1] + i;
        if (g < (unsigned)CAP) gb1[g] = lb1[i];
    }
    for (int o = 32; o > 0; o >>= 1) { rs0 += __shfl_down(rs0, o); rs1 += __shfl_down(rs1, o); }
    const int wid = tid >> 6;
    if (lane == 0) { wred[wid] = rs0; wred[4+wid] = rs1; }
    __syncthreads();
    if (tid == 0) {
        float s0 = wred[0]+wred[1]+wred[2]+wred[3];
        float s1 = wred[4]+wred[5]+wred[6]+wred[7];
        unsafeAtomicAdd(&sumAbove[b*2+0], (double)s0);
        unsafeAtomicAdd(&sumAbove[b*2+1], (double)s1);
    }
}

// ---------------------------------------------------------------------------
// Refine: per channel, two in-LDS histogram rounds over the compact buffer
// (bits[18:8] then bits[7:0]), exact threshold, f64 sum above it.
// Last block (done-counter) also performs the final 64-channel reduction.
// ---------------------------------------------------------------------------
__global__ __launch_bounds__(256) void k_refine(
    const float* __restrict__ cbuf, const unsigned* __restrict__ ccnt,
    const unsigned* __restrict__ T1, const unsigned* __restrict__ rem1,
    const unsigned* __restrict__ kk, const float* __restrict__ posi,
    const double* __restrict__ sumAbove,
    float* __restrict__ contrib,
    unsigned* __restrict__ done, float* __restrict__ out)
{
    const int ch = blockIdx.x;
    const int tid = threadIdx.x;
    const unsigned k = kk[ch];

    auto finish = [&](float cval) {
        // tid == 0 only
        contrib[ch] = cval;
        __threadfence();
        const unsigned d = atomicAdd(done, 1u);
        if (d == (unsigned)CH2 - 1u) {          // last channel done -> reduce
            __threadfence();
            double acc = 0.0;
            for (int i = 0; i < CH2; ++i) acc += (double)contrib[i];
            out[0] = (float)(acc / (double)BATCH);
        }
    };

    if (k == 0u) {
        if (tid == 0) finish(posi[ch]);
        return;
    }
    unsigned cnt = ccnt[ch];
    if (cnt > (unsigned)CAP) cnt = (unsigned)CAP;
    const float* buf = cbuf + (size_t)ch * CAP;

    __shared__ unsigned hA[NB1];
    __shared__ unsigned hB[256];
    __shared__ double   wsum[4];
    for (int j = tid; j < NB1; j += 256) hA[j] = 0u;
    __syncthreads();
    for (unsigned i = tid; i < cnt; i += 256) {
        const unsigned bt = __float_as_uint(buf[i]);
        atomicAdd(&hA[(bt >> 8) & 2047u], 1u);
    }
    __syncthreads();
    unsigned T2, rem2;
    select_counts<NB1>(hA, rem1[ch], T2, rem2);

    hB[tid] = 0u;
    __syncthreads();
    for (unsigned i = tid; i < cnt; i += 256) {
        const unsigned bt = __float_as_uint(buf[i]);
        if (((bt >> 8) & 2047u) == T2) atomicAdd(&hB[bt & 255u], 1u);
    }
    __syncthreads();
    unsigned T3, rem3;
    select_counts<256>(hB, rem2, T3, rem3);

    const float t = __uint_as_float((T1[ch] << 19) | (T2 << 8) | T3);
    double s = 0.0;
    for (unsigned i = tid; i < cnt; i += 256) {
        const float v = buf[i];
        if (v > t) s += (double)v;
    }
    for (int o = 32; o > 0; o >>= 1) s += __shfl_down(s, o);
    const int wid = tid >> 6, lane = tid & 63;
    if (lane == 0) wsum[wid] = s;
    __syncthreads();
    if (tid == 0) {
        const double stop = wsum[0] + wsum[1] + wsum[2] + wsum[3];
        const double nega = (sumAbove[ch] + stop + (double)rem3 * (double)t) / (double)k;
        finish((float)((double)posi[ch] + nega));
    }
}

// ---------------------------------------------------------------------------
extern "C" void kernel_launch(void* const* d_in, const int* in_sizes, int n_in,
                              void* d_out, int out_size, void* d_ws, size_t ws_size,
                              hipStream_t stream)
{
    (void)in_sizes; (void)n_in; (void)out_size; (void)ws_size;
    const float4* pred4 = (const float4*)d_in[0];
    const float4* reg4  = (const float4*)d_in[1];
    const float4* aff4  = (const float4*)d_in[2];

    char* w = (char*)d_ws;
    unsigned* h1c  = (unsigned*)w;                        // 64*2048 u32 = 512 KB
    unsigned* pcnt = h1c + (size_t)CH2 * NB1;
    float*    psum = (float*)(pcnt + CH2);
    unsigned* T1   = (unsigned*)(psum + CH2);
    unsigned* rem1 = T1 + CH2;
    unsigned* kk   = rem1 + CH2;
    float*    posi = (float*)(kk + CH2);
    float*    contrib = posi + CH2;
    unsigned* ccnt = (unsigned*)(contrib + CH2);
    double*   sumAbove = (double*)(ccnt + CH2);           // offset divisible by 8
    unsigned* done = (unsigned*)(sumAbove + CH2);
    const size_t hdr_bytes = (size_t)((char*)(done + 1) - w);  // ~527 KB

    float* cbuf = (float*)(w + ((size_t)1 << 20));        // 33.5 MB at +1 MB

    hipMemsetAsync(d_ws, 0, hdr_bytes, stream);

    dim3 grid(BX, BATCH);
    k_hist<<<grid, 256, 0, stream>>>(pred4, reg4, aff4, h1c, pcnt, psum);
    k_scan1<<<CH2, 256, 0, stream>>>(h1c, pcnt, psum, T1, rem1, kk, posi);
    k_compact<<<grid, 256, 0, stream>>>(pred4, reg4, aff4, T1, cbuf, ccnt, sumAbove);
    k_refine<<<CH2, 256, 0, stream>>>(cbuf, ccnt, T1, rem1, kk, posi, sumAbove,
                                      contrib, done, (float*)d_out);
}